// Round 4
// baseline (443.462 us; speedup 1.0000x reference)
//
#include <hip/hip_runtime.h>

#define NN 50000
#define NP 50176        // padded node stride (multiple of 256)
#define TT 518
#define KC 32
#define LL 163
#define HH 128
#define EE 1600000
#define NB 196          // node blocks: 196*256 = 50176 >= NN
#define NCOPY 8

// ---- chunked-LDS scatter (no global atomics) ----
#define CKN 4           // node chunks
#define CSZ 12544      // nodes/chunk (4*12544 = 50176), LDS acc = 50176 B
#define PSL 64          // edge slices (partials per chunk); part = 12.8MB
#define GSC (CKN*PSL)   // 256 blocks = 1/CU
#define ESL (EE/PSL)    // 25000 edges per slice (divisible by 4)

// ---- conv5: rolling-53-window conv ----
// R3 lesson: allocator batches loads only if the live window fits comfortably
// under the VGPR cap.  197-float window -> 1-2 loads in flight (1.57 TB/s).
// 53-float window (the 268us ancestor's shape) -> fully batched, ~5.2 TB/s.
#define G5 3            // l-groups: grid = NB*G5 = 588 blocks
#define C5 7            // chunks per group; G5*C5*8 = 168 l's >= 163
#define W5 53           // rolling register window (3*7+32)
#define VS 16           // v accumulator stripes
#define VSTR 192        // stripe stride (>= LL, 16B-aligned)

// deg partials: block (chunk=b&3, p=b>>2) scans slice p, bins col hits into
// LDS, flushes private partial with plain stores.
__global__ __launch_bounds__(256) void k_deg_part(const int* __restrict__ col,
                                                  const float* __restrict__ ea,
                                                  float* __restrict__ part) {
  __shared__ float acc[CSZ];
  int tid = threadIdx.x;
  for (int j = tid; j < CSZ; j += 256) acc[j] = 0.f;
  __syncthreads();
  int chunk = blockIdx.x & (CKN - 1);
  int base = chunk * CSZ;
  const int4*   c4p = (const int4*)col + (blockIdx.x >> 2) * (ESL / 4);
  const float4* a4p = (const float4*)ea + (blockIdx.x >> 2) * (ESL / 4);
  for (int i = tid; i < ESL / 4; i += 256) {
    int4   c4 = c4p[i];
    float4 a4 = a4p[i];
    unsigned jx = (unsigned)(c4.x - base);
    unsigned jy = (unsigned)(c4.y - base);
    unsigned jz = (unsigned)(c4.z - base);
    unsigned jw = (unsigned)(c4.w - base);
    if (jx < CSZ) atomicAdd(&acc[jx], a4.x);
    if (jy < CSZ) atomicAdd(&acc[jy], a4.y);
    if (jz < CSZ) atomicAdd(&acc[jz], a4.z);
    if (jw < CSZ) atomicAdd(&acc[jw], a4.w);
  }
  __syncthreads();
  float* out = part + (size_t)blockIdx.x * CSZ;
  for (int j = tid; j < CSZ; j += 256) out[j] = acc[j];
}

// dinv[i] = rsqrt(1 + sum_p degpart[p][i]); 4 accumulators for ILP
__global__ __launch_bounds__(256) void k_dinv2(const float* __restrict__ part,
                                               float* __restrict__ dinv) {
  int i = blockIdx.x * 256 + threadIdx.x;
  if (i >= NN) return;
  int chunk = i / CSZ, j = i - chunk * CSZ;
  const float* q = part + (size_t)chunk * CSZ + j;
  float s0 = 0.f, s1 = 0.f, s2 = 0.f, s3 = 0.f;
#pragma unroll
  for (int p = 0; p < PSL; p += 4) {
    s0 += q[(size_t)(p + 0) * (CKN * CSZ)];
    s1 += q[(size_t)(p + 1) * (CKN * CSZ)];
    s2 += q[(size_t)(p + 2) * (CKN * CSZ)];
    s3 += q[(size_t)(p + 3) * (CKN * CSZ)];
  }
  dinv[i] = rsqrtf(1.0f + (s0 + s1) + (s2 + s3));
}

// coef partials: acc[row] += ea * dinv[col].  dinv[row] folded into k_csum2.
__global__ __launch_bounds__(256) void k_coef_part(const int* __restrict__ row,
                                                   const int* __restrict__ col,
                                                   const float* __restrict__ ea,
                                                   const float* __restrict__ dinv,
                                                   float* __restrict__ part) {
  __shared__ float acc[CSZ];
  int tid = threadIdx.x;
  for (int j = tid; j < CSZ; j += 256) acc[j] = 0.f;
  __syncthreads();
  int chunk = blockIdx.x & (CKN - 1);
  int base = chunk * CSZ;
  const int4*   r4p = (const int4*)row + (blockIdx.x >> 2) * (ESL / 4);
  const int4*   c4p = (const int4*)col + (blockIdx.x >> 2) * (ESL / 4);
  const float4* a4p = (const float4*)ea + (blockIdx.x >> 2) * (ESL / 4);
  for (int i = tid; i < ESL / 4; i += 256) {
    int4   r4 = r4p[i];
    int4   c4 = c4p[i];
    float4 a4 = a4p[i];
    unsigned jx = (unsigned)(r4.x - base);
    unsigned jy = (unsigned)(r4.y - base);
    unsigned jz = (unsigned)(r4.z - base);
    unsigned jw = (unsigned)(r4.w - base);
    if (jx < CSZ) atomicAdd(&acc[jx], a4.x * dinv[c4.x]);
    if (jy < CSZ) atomicAdd(&acc[jy], a4.y * dinv[c4.y]);
    if (jz < CSZ) atomicAdd(&acc[jz], a4.z * dinv[c4.z]);
    if (jw < CSZ) atomicAdd(&acc[jw], a4.w * dinv[c4.w]);
  }
  __syncthreads();
  float* out = part + (size_t)blockIdx.x * CSZ;
  for (int j = tid; j < CSZ; j += 256) out[j] = acc[j];
}

// c[i] = dinv[i]^2 + dinv[i] * sum_p coefpart[p][i]
__global__ __launch_bounds__(256) void k_csum2(const float* __restrict__ part,
                                               const float* __restrict__ dinv,
                                               float* __restrict__ c) {
  int i = blockIdx.x * 256 + threadIdx.x;
  if (i >= NN) return;
  int chunk = i / CSZ, j = i - chunk * CSZ;
  const float* q = part + (size_t)chunk * CSZ + j;
  float s0 = 0.f, s1 = 0.f, s2 = 0.f, s3 = 0.f;
#pragma unroll
  for (int p = 0; p < PSL; p += 4) {
    s0 += q[(size_t)(p + 0) * (CKN * CSZ)];
    s1 += q[(size_t)(p + 1) * (CKN * CSZ)];
    s2 += q[(size_t)(p + 2) * (CKN * CSZ)];
    s3 += q[(size_t)(p + 3) * (CKN * CSZ)];
  }
  float di = dinv[i];
  c[i] = di * di + di * ((s0 + s1) + (s2 + s3));
}

// ---- fallback path (global-atomic version) if ws is too small ----
__global__ __launch_bounds__(256) void k_deg(const int* __restrict__ col,
                                             const float* __restrict__ ea,
                                             float* __restrict__ deg8) {
  int i = blockIdx.x * 256 + threadIdx.x;
  float* d = deg8 + (blockIdx.x & 7) * NP;
  if (i < EE / 4) {
    int4   c4 = ((const int4*)col)[i];
    float4 a4 = ((const float4*)ea)[i];
    atomicAdd(&d[c4.x], a4.x);
    atomicAdd(&d[c4.y], a4.y);
    atomicAdd(&d[c4.z], a4.z);
    atomicAdd(&d[c4.w], a4.w);
  }
}
__global__ __launch_bounds__(256) void k_dinv(const float* __restrict__ deg8,
                                              float* __restrict__ dinv) {
  int i = blockIdx.x * 256 + threadIdx.x;
  if (i < NN) {
    float s = 1.0f;
#pragma unroll
    for (int j = 0; j < NCOPY; ++j) s += deg8[j * NP + i];
    dinv[i] = rsqrtf(s);
  }
}
__global__ __launch_bounds__(256) void k_coef(const int* __restrict__ row,
                                              const int* __restrict__ col,
                                              const float* __restrict__ ea,
                                              const float* __restrict__ dinv,
                                              float* __restrict__ coef8) {
  int i = blockIdx.x * 256 + threadIdx.x;
  float* cf = coef8 + (blockIdx.x & 7) * NP;
  if (i < EE / 4) {
    int4   r4 = ((const int4*)row)[i];
    int4   c4 = ((const int4*)col)[i];
    float4 a4 = ((const float4*)ea)[i];
    atomicAdd(&cf[r4.x], a4.x * dinv[c4.x] * dinv[r4.x]);
    atomicAdd(&cf[r4.y], a4.y * dinv[c4.y] * dinv[r4.y]);
    atomicAdd(&cf[r4.z], a4.z * dinv[c4.z] * dinv[r4.z]);
    atomicAdd(&cf[r4.w], a4.w * dinv[c4.w] * dinv[r4.w]);
  }
}
__global__ __launch_bounds__(256) void k_csum(const float* __restrict__ coef8,
                                              const float* __restrict__ dinv,
                                              float* __restrict__ c) {
  int i = blockIdx.x * 256 + threadIdx.x;
  if (i < NN) {
    float di = dinv[i];
    float s = di * di;
#pragma unroll
    for (int j = 0; j < NCOPY; ++j) s += coef8[j * NP + i];
    c[i] = s;
  }
}

// v[l] += sum_n c[n]*relu(conv(x,w)+b)[l].
// conv5: thread = node (256B/wave coalesced).  Block (nb, g) computes
// 56 l's (C5=7 chunks x 8) for nodes nb*256..+255 using a ROLLING 53-float
// register window: per chunk, compute 8 l's, shift window down 24 (29 movs),
// load 24 new values.  Live set ~108 VGPR -> allocator keeps loads batched
// (R3: 101-float window forced load/use chaining at VGPR=128 -> 1.57 TB/s;
// the 53-float shape is the ancestor's proven ~5.2 TB/s batch size).
// Traffic: x 197*3/518 = 1.14x (118 MB, L3-resident) + w 3x (19 MB).
// 588 blocks, 4 waves/SIMD -> ~16 waves/CU: TLP covers the per-chunk
// 24-load latency under the ~290ns compute phase.
__global__ __launch_bounds__(256, 4) void k_conv5(const float* __restrict__ x,
                                                  const float* __restrict__ cw,
                                                  const float* __restrict__ cb,
                                                  const float* __restrict__ c,
                                                  float* __restrict__ v16) {
  __shared__ float vloc[56];
  int tid = threadIdx.x;
  if (tid < 56) vloc[tid] = 0.f;
  __syncthreads();

  int nb = blockIdx.x % NB;
  int g  = blockIdx.x / NB;        // 0..2
  int n = nb * 256 + tid;
  int nc = n < NN ? n : NN - 1;    // clamp for safe loads; cn=0 kills contrib
  float cn = n < NN ? c[n] : 0.f;
  float bn = cb[nc];

  float w[KC];
  const float4* w4 = (const float4*)(cw + (size_t)nc * KC);
#pragma unroll
  for (int k = 0; k < KC / 4; ++k) {
    float4 t = w4[k];
    w[4 * k] = t.x; w[4 * k + 1] = t.y; w[4 * k + 2] = t.z; w[4 * k + 3] = t.w;
  }

  const float* xp = x + nc;
  int start = 168 * g;
  float xs[W5];
#pragma unroll
  for (int j = 0; j < W5; ++j) {
    int t = start + j;
    t = t < TT ? t : TT - 1;       // generic clamp (free; only g=2 tail hits)
    xs[j] = xp[(size_t)t * NN];
  }
  __builtin_amdgcn_sched_barrier(0);   // initial loads stay batched above

  int lane = tid & 63;
#pragma unroll
  for (int cc = 0; cc < C5; ++cc) {
    // compute 8 l's: l = 56g + 8cc + u, window holds t = start+24cc + [0,53)
    float accv[8];
#pragma unroll
    for (int u = 0; u < 8; ++u) {
      float h = 0.f;
#pragma unroll
      for (int k = 0; k < KC; ++k) h += xs[3 * u + k] * w[k];
      h += bn;
      h = h > 0.f ? h : 0.f;
      accv[u] = cn * h;
    }
#pragma unroll
    for (int u = 0; u < 8; ++u) {
      float val = accv[u];
      val += __shfl_xor(val, 1, 64);
      val += __shfl_xor(val, 2, 64);
      val += __shfl_xor(val, 4, 64);
      val += __shfl_xor(val, 8, 64);
      val += __shfl_xor(val, 16, 64);
      val += __shfl_xor(val, 32, 64);
      if (lane == 0) atomicAdd(&vloc[8 * cc + u], val);
    }
    // roll window: keep top 29, load 24 new (t = start+24cc+53 .. +76)
    if (cc < C5 - 1) {
#pragma unroll
      for (int j = 0; j < W5 - 24; ++j) xs[j] = xs[j + 24];
#pragma unroll
      for (int j = 0; j < 24; ++j) {
        int t = start + 24 * cc + W5 + j;
        t = t < TT ? t : TT - 1;   // clamp pollutes only l >= 163
        xs[W5 - 24 + j] = xp[(size_t)t * NN];
      }
    }
  }
  __syncthreads();
  float* vdst = v16 + (blockIdx.x & (VS - 1)) * VSTR;
  if (tid < 56) {
    int l = 56 * g + tid;
    if (l < LL) atomicAdd(&vdst[l], vloc[tid]);
  }
}

// out[h] = (sum_l (sum_j v16[j][l]) * W[l][h]) / N + gcn_b[h]
__global__ __launch_bounds__(128) void k_out(const float* __restrict__ v16,
                                             const float* __restrict__ W,
                                             const float* __restrict__ b,
                                             float* __restrict__ out) {
  __shared__ float vs[LL];
  int h = threadIdx.x;
  for (int l = h; l < LL; l += 128) {
    float s = 0.f;
#pragma unroll
    for (int j = 0; j < VS; ++j) s += v16[j * VSTR + l];
    vs[l] = s;
  }
  __syncthreads();
  float s = 0.f;
  for (int l = 0; l < LL; ++l) s += vs[l] * W[l * HH + h];
  out[h] = s * (1.0f / NN) + b[h];
}

extern "C" void kernel_launch(void* const* d_in, const int* in_sizes, int n_in,
                              void* d_out, int out_size, void* d_ws, size_t ws_size,
                              hipStream_t stream) {
  const float* x  = (const float*)d_in[0];
  const int*   ei = (const int*)d_in[1];
  const float* ea = (const float*)d_in[2];
  const float* cw = (const float*)d_in[3];
  const float* cb = (const float*)d_in[4];
  const float* gW = (const float*)d_in[5];
  const float* gb = (const float*)d_in[6];
  float* out = (float*)d_out;

  const int* row = ei;
  const int* col = ei + EE;
  float* ws = (float*)d_ws;

  size_t need_new = ((size_t)GSC * CSZ + VS * VSTR + 2 * NP) * sizeof(float);
  if (ws_size >= need_new) {
    float* part = ws;                          // GSC*CSZ floats (reused deg->coef)
    float* v16  = ws + (size_t)GSC * CSZ;      // VS*VSTR floats
    float* dinv = v16 + VS * VSTR;             // NP floats
    float* c    = dinv + NP;                   // NP floats
    hipMemsetAsync(v16, 0, VS * VSTR * sizeof(float), stream);
    k_deg_part <<<GSC, 256, 0, stream>>>(col, ea, part);
    k_dinv2    <<<NB, 256, 0, stream>>>(part, dinv);
    k_coef_part<<<GSC, 256, 0, stream>>>(row, col, ea, dinv, part);
    k_csum2    <<<NB, 256, 0, stream>>>(part, dinv, c);
    k_conv5    <<<NB * G5, 256, 0, stream>>>(x, cw, cb, c, v16);
    k_out      <<<1, 128, 0, stream>>>(v16, gW, gb, out);
  } else {
    float* deg8  = ws;
    float* coef8 = ws + NCOPY * NP;
    float* v16   = ws + 2 * NCOPY * NP;
    float* dinv  = ws + 2 * NCOPY * NP + VS * VSTR;
    float* c     = dinv + NP;
    hipMemsetAsync(deg8, 0, (2 * NCOPY * NP + VS * VSTR) * sizeof(float), stream);
    int egrid = (EE / 4 + 255) / 256;
    k_deg  <<<egrid, 256, 0, stream>>>(col, ea, deg8);
    k_dinv <<<NB, 256, 0, stream>>>(deg8, dinv);
    k_coef <<<egrid, 256, 0, stream>>>(row, col, ea, dinv, coef8);
    k_csum <<<NB, 256, 0, stream>>>(coef8, dinv, c);
    k_conv5<<<NB * G5, 256, 0, stream>>>(x, cw, cb, c, v16);
    k_out  <<<1, 128, 0, stream>>>(v16, gW, gb, out);
  }
}

// Round 5
// 276.888 us; speedup vs baseline: 1.6016x; 1.6016x over previous
//
#include <hip/hip_runtime.h>

#define NN 50000
#define NP 50176        // padded node stride (multiple of 256)
#define TT 518
#define KC 32
#define LL 163
#define HH 128
#define EE 1600000
#define NB 196          // node blocks: 196*256 = 50176 >= NN
#define NCOPY 8

// ---- chunked-LDS scatter (no global atomics) ----
// PSL=128 restored: R3's PSL=64 gave only 256 scatter blocks (1/CU) and the
// "rest" of the pipeline regressed ~7-14us.  512 blocks = 2/CU is the proven
// R0 config.
#define CKN 4           // node chunks
#define CSZ 12544       // nodes/chunk (4*12544 = 50176), LDS acc = 50176 B
#define PSL 128         // edge slices (partials per chunk)
#define GSC (CKN*PSL)   // 512 blocks
#define ESL (EE/PSL)    // 12500 edges per slice (divisible by 4)

// ---- conv6: conv4 geometry + LDS-staged weights ----
#define GRP 7           // l-groups, one block each: grid = NB*GRP = 1372
#define LPB 24          // l's per block (7*24 = 168 >= 163)
#define WIN 101         // window: 3*23 + 32 = 101 floats
#define WPAD 33         // padded w stride in LDS: bank=(tid+k)%32, conflict-free
#define VS 16           // v accumulator stripes
#define VSTR 192        // stripe stride (>= LL, 16B-aligned)

// deg partials: block (chunk=b&3, p=b>>2) scans slice p, bins col hits into
// LDS, flushes private partial with plain stores.
__global__ __launch_bounds__(256) void k_deg_part(const int* __restrict__ col,
                                                  const float* __restrict__ ea,
                                                  float* __restrict__ part) {
  __shared__ float acc[CSZ];
  int tid = threadIdx.x;
  for (int j = tid; j < CSZ; j += 256) acc[j] = 0.f;
  __syncthreads();
  int chunk = blockIdx.x & (CKN - 1);
  int base = chunk * CSZ;
  const int4*   c4p = (const int4*)col + (blockIdx.x >> 2) * (ESL / 4);
  const float4* a4p = (const float4*)ea + (blockIdx.x >> 2) * (ESL / 4);
  for (int i = tid; i < ESL / 4; i += 256) {
    int4   c4 = c4p[i];
    float4 a4 = a4p[i];
    unsigned jx = (unsigned)(c4.x - base);
    unsigned jy = (unsigned)(c4.y - base);
    unsigned jz = (unsigned)(c4.z - base);
    unsigned jw = (unsigned)(c4.w - base);
    if (jx < CSZ) atomicAdd(&acc[jx], a4.x);
    if (jy < CSZ) atomicAdd(&acc[jy], a4.y);
    if (jz < CSZ) atomicAdd(&acc[jz], a4.z);
    if (jw < CSZ) atomicAdd(&acc[jw], a4.w);
  }
  __syncthreads();
  float* out = part + (size_t)blockIdx.x * CSZ;
  for (int j = tid; j < CSZ; j += 256) out[j] = acc[j];
}

// dinv[i] = rsqrt(1 + sum_p degpart[p][i]); 4 accumulators for ILP.
// Also zeroes v16 (first 12 blocks) -> saves the memset dispatch.
__global__ __launch_bounds__(256) void k_dinv2(const float* __restrict__ part,
                                               float* __restrict__ dinv,
                                               float* __restrict__ v16) {
  int tid = threadIdx.x;
  if (blockIdx.x < (VS * VSTR) / 256) v16[blockIdx.x * 256 + tid] = 0.f;
  int i = blockIdx.x * 256 + tid;
  if (i >= NN) return;
  int chunk = i / CSZ, j = i - chunk * CSZ;
  const float* q = part + (size_t)chunk * CSZ + j;
  float s0 = 0.f, s1 = 0.f, s2 = 0.f, s3 = 0.f;
#pragma unroll
  for (int p = 0; p < PSL; p += 4) {
    s0 += q[(size_t)(p + 0) * (CKN * CSZ)];
    s1 += q[(size_t)(p + 1) * (CKN * CSZ)];
    s2 += q[(size_t)(p + 2) * (CKN * CSZ)];
    s3 += q[(size_t)(p + 3) * (CKN * CSZ)];
  }
  dinv[i] = rsqrtf(1.0f + (s0 + s1) + (s2 + s3));
}

// coef partials: acc[row] += ea * dinv[col].  dinv[row] folded into k_csum2.
__global__ __launch_bounds__(256) void k_coef_part(const int* __restrict__ row,
                                                   const int* __restrict__ col,
                                                   const float* __restrict__ ea,
                                                   const float* __restrict__ dinv,
                                                   float* __restrict__ part) {
  __shared__ float acc[CSZ];
  int tid = threadIdx.x;
  for (int j = tid; j < CSZ; j += 256) acc[j] = 0.f;
  __syncthreads();
  int chunk = blockIdx.x & (CKN - 1);
  int base = chunk * CSZ;
  const int4*   r4p = (const int4*)row + (blockIdx.x >> 2) * (ESL / 4);
  const int4*   c4p = (const int4*)col + (blockIdx.x >> 2) * (ESL / 4);
  const float4* a4p = (const float4*)ea + (blockIdx.x >> 2) * (ESL / 4);
  for (int i = tid; i < ESL / 4; i += 256) {
    int4   r4 = r4p[i];
    int4   c4 = c4p[i];
    float4 a4 = a4p[i];
    unsigned jx = (unsigned)(r4.x - base);
    unsigned jy = (unsigned)(r4.y - base);
    unsigned jz = (unsigned)(r4.z - base);
    unsigned jw = (unsigned)(r4.w - base);
    if (jx < CSZ) atomicAdd(&acc[jx], a4.x * dinv[c4.x]);
    if (jy < CSZ) atomicAdd(&acc[jy], a4.y * dinv[c4.y]);
    if (jz < CSZ) atomicAdd(&acc[jz], a4.z * dinv[c4.z]);
    if (jw < CSZ) atomicAdd(&acc[jw], a4.w * dinv[c4.w]);
  }
  __syncthreads();
  float* out = part + (size_t)blockIdx.x * CSZ;
  for (int j = tid; j < CSZ; j += 256) out[j] = acc[j];
}

// c[i] = dinv[i]^2 + dinv[i] * sum_p coefpart[p][i]
__global__ __launch_bounds__(256) void k_csum2(const float* __restrict__ part,
                                               const float* __restrict__ dinv,
                                               float* __restrict__ c) {
  int i = blockIdx.x * 256 + threadIdx.x;
  if (i >= NN) return;
  int chunk = i / CSZ, j = i - chunk * CSZ;
  const float* q = part + (size_t)chunk * CSZ + j;
  float s0 = 0.f, s1 = 0.f, s2 = 0.f, s3 = 0.f;
#pragma unroll
  for (int p = 0; p < PSL; p += 4) {
    s0 += q[(size_t)(p + 0) * (CKN * CSZ)];
    s1 += q[(size_t)(p + 1) * (CKN * CSZ)];
    s2 += q[(size_t)(p + 2) * (CKN * CSZ)];
    s3 += q[(size_t)(p + 3) * (CKN * CSZ)];
  }
  float di = dinv[i];
  c[i] = di * di + di * ((s0 + s1) + (s2 + s3));
}

// ---- fallback path (global-atomic version) if ws is too small ----
__global__ __launch_bounds__(256) void k_deg(const int* __restrict__ col,
                                             const float* __restrict__ ea,
                                             float* __restrict__ deg8) {
  int i = blockIdx.x * 256 + threadIdx.x;
  float* d = deg8 + (blockIdx.x & 7) * NP;
  if (i < EE / 4) {
    int4   c4 = ((const int4*)col)[i];
    float4 a4 = ((const float4*)ea)[i];
    atomicAdd(&d[c4.x], a4.x);
    atomicAdd(&d[c4.y], a4.y);
    atomicAdd(&d[c4.z], a4.z);
    atomicAdd(&d[c4.w], a4.w);
  }
}
__global__ __launch_bounds__(256) void k_dinv(const float* __restrict__ deg8,
                                              float* __restrict__ dinv) {
  int i = blockIdx.x * 256 + threadIdx.x;
  if (i < NN) {
    float s = 1.0f;
#pragma unroll
    for (int j = 0; j < NCOPY; ++j) s += deg8[j * NP + i];
    dinv[i] = rsqrtf(s);
  }
}
__global__ __launch_bounds__(256) void k_coef(const int* __restrict__ row,
                                              const int* __restrict__ col,
                                              const float* __restrict__ ea,
                                              const float* __restrict__ dinv,
                                              float* __restrict__ coef8) {
  int i = blockIdx.x * 256 + threadIdx.x;
  float* cf = coef8 + (blockIdx.x & 7) * NP;
  if (i < EE / 4) {
    int4   r4 = ((const int4*)row)[i];
    int4   c4 = ((const int4*)col)[i];
    float4 a4 = ((const float4*)ea)[i];
    atomicAdd(&cf[r4.x], a4.x * dinv[c4.x] * dinv[r4.x]);
    atomicAdd(&cf[r4.y], a4.y * dinv[c4.y] * dinv[r4.y]);
    atomicAdd(&cf[r4.z], a4.z * dinv[c4.z] * dinv[r4.z]);
    atomicAdd(&cf[r4.w], a4.w * dinv[c4.w] * dinv[r4.w]);
  }
}
__global__ __launch_bounds__(256) void k_csum(const float* __restrict__ coef8,
                                              const float* __restrict__ dinv,
                                              float* __restrict__ c) {
  int i = blockIdx.x * 256 + threadIdx.x;
  if (i < NN) {
    float di = dinv[i];
    float s = di * di;
#pragma unroll
    for (int j = 0; j < NCOPY; ++j) s += coef8[j * NP + i];
    c[i] = s;
  }
}

// v[l] += sum_n c[n]*relu(conv(x,w)+b)[l].
// conv6 = conv4 (verified 60.3us) + ONE isolated change: the w-load.
// conv4's only uncoalesced access was lane i gathering cw[(n0+i)*32+4k]
// (128B lane stride: each float4 inst touches 64 cache lines ~= 512 TA
// cycles/wave, rivaling all 101 x-loads, + 4x sector overfetch on 45MB).
// conv6 stages the block's 32KB w-slab into LDS with coalesced float4
// loads (1024B/inst contiguous), then reads w via +1-padded LDS
// (stride 33 -> bank=(tid+k)%32, 2 lanes/bank = free).
// R4 lesson kept: NO register-array shifting (conv5 spilled to scratch).
__global__ __launch_bounds__(256, 2) void k_conv6(const float* __restrict__ x,
                                                  const float* __restrict__ cw,
                                                  const float* __restrict__ cb,
                                                  const float* __restrict__ c,
                                                  float* __restrict__ v16) {
  __shared__ float vloc[LPB];
  __shared__ float wl[256 * WPAD];   // 33.8 KB
  int tid = threadIdx.x;
  if (tid < LPB) vloc[tid] = 0.f;

  int nb = blockIdx.x % NB;
  int g  = blockIdx.x / NB;        // 0..6
  int n = nb * 256 + tid;
  int nc = n < NN ? n : NN - 1;    // clamp for safe loads; cn=0 kills contrib
  float cn = n < NN ? c[n] : 0.f;
  float bn = cb[nc];

  // x register window first (issues 101 coalesced loads, stays in flight
  // while w staging proceeds): t in [72g, 72g+101)
  const float* xp = x + nc;
  float xs[WIN];
#pragma unroll
  for (int j = 0; j < WIN; ++j) {
    int t = 72 * g + j;
    t = t < TT ? t : TT - 1;       // clamp pollutes only l >= 163
    xs[j] = xp[(size_t)t * NN];
  }

  // cooperative w staging: block's 256 nodes * 8 float4 = 2048 float4,
  // perfectly coalesced.  Tail block clamps SOURCE (finite data; those
  // nodes have cn=0) to avoid OOB and NaN-from-uninitialized-LDS.
  const float4* cw4 = (const float4*)cw;
  int base4 = nb * 2048;
#pragma unroll
  for (int it = 0; it < 8; ++it) {
    int j4 = it * 256 + tid;
    int src = base4 + j4;
    if (src > NN * 8 - 1) src = NN * 8 - 1;
    float4 t = cw4[src];
    int nn = j4 >> 3;
    int k  = (j4 & 7) * 4;
    float* d = &wl[nn * WPAD + k];
    d[0] = t.x; d[1] = t.y; d[2] = t.z; d[3] = t.w;
  }
  __syncthreads();

  float w[KC];
#pragma unroll
  for (int k = 0; k < KC; ++k) w[k] = wl[tid * WPAD + k];
  __builtin_amdgcn_sched_barrier(0);   // loads stay ABOVE, compute BELOW

  int lane = tid & 63;
#pragma unroll
  for (int cc = 0; cc < 3; ++cc) {
    float accv[8];
#pragma unroll
    for (int u = 0; u < 8; ++u) {
      float h = 0.f;
#pragma unroll
      for (int k = 0; k < KC; ++k) h += xs[24 * cc + 3 * u + k] * w[k];
      h += bn;
      h = h > 0.f ? h : 0.f;
      accv[u] = cn * h;
    }
#pragma unroll
    for (int u = 0; u < 8; ++u) {
      float val = accv[u];
      val += __shfl_xor(val, 1, 64);
      val += __shfl_xor(val, 2, 64);
      val += __shfl_xor(val, 4, 64);
      val += __shfl_xor(val, 8, 64);
      val += __shfl_xor(val, 16, 64);
      val += __shfl_xor(val, 32, 64);
      if (lane == 0) atomicAdd(&vloc[8 * cc + u], val);
    }
  }
  __syncthreads();
  float* vdst = v16 + (blockIdx.x & (VS - 1)) * VSTR;
  if (tid < LPB) {
    int l = LPB * g + tid;
    if (l < LL) atomicAdd(&vdst[l], vloc[tid]);
  }
}

// out[h] = (sum_l (sum_j v16[j][l]) * W[l][h]) / N + gcn_b[h]
__global__ __launch_bounds__(128) void k_out(const float* __restrict__ v16,
                                             const float* __restrict__ W,
                                             const float* __restrict__ b,
                                             float* __restrict__ out) {
  __shared__ float vs[LL];
  int h = threadIdx.x;
  for (int l = h; l < LL; l += 128) {
    float s = 0.f;
#pragma unroll
    for (int j = 0; j < VS; ++j) s += v16[j * VSTR + l];
    vs[l] = s;
  }
  __syncthreads();
  float s = 0.f;
  for (int l = 0; l < LL; ++l) s += vs[l] * W[l * HH + h];
  out[h] = s * (1.0f / NN) + b[h];
}

extern "C" void kernel_launch(void* const* d_in, const int* in_sizes, int n_in,
                              void* d_out, int out_size, void* d_ws, size_t ws_size,
                              hipStream_t stream) {
  const float* x  = (const float*)d_in[0];
  const int*   ei = (const int*)d_in[1];
  const float* ea = (const float*)d_in[2];
  const float* cw = (const float*)d_in[3];
  const float* cb = (const float*)d_in[4];
  const float* gW = (const float*)d_in[5];
  const float* gb = (const float*)d_in[6];
  float* out = (float*)d_out;

  const int* row = ei;
  const int* col = ei + EE;
  float* ws = (float*)d_ws;

  size_t need_new = ((size_t)GSC * CSZ + VS * VSTR + 2 * NP) * sizeof(float);
  if (ws_size >= need_new) {
    float* part = ws;                          // GSC*CSZ floats (reused deg->coef)
    float* v16  = ws + (size_t)GSC * CSZ;      // VS*VSTR floats
    float* dinv = v16 + VS * VSTR;             // NP floats
    float* c    = dinv + NP;                   // NP floats
    k_deg_part <<<GSC, 256, 0, stream>>>(col, ea, part);
    k_dinv2    <<<NB, 256, 0, stream>>>(part, dinv, v16);
    k_coef_part<<<GSC, 256, 0, stream>>>(row, col, ea, dinv, part);
    k_csum2    <<<NB, 256, 0, stream>>>(part, dinv, c);
    k_conv6    <<<NB * GRP, 256, 0, stream>>>(x, cw, cb, c, v16);
    k_out      <<<1, 128, 0, stream>>>(v16, gW, gb, out);
  } else {
    float* deg8  = ws;
    float* coef8 = ws + NCOPY * NP;
    float* v16   = ws + 2 * NCOPY * NP;
    float* dinv  = v16 + VS * VSTR;
    float* c     = dinv + NP;
    hipMemsetAsync(deg8, 0, (2 * NCOPY * NP + VS * VSTR) * sizeof(float), stream);
    int egrid = (EE / 4 + 255) / 256;
    k_deg  <<<egrid, 256, 0, stream>>>(col, ea, deg8);
    k_dinv <<<NB, 256, 0, stream>>>(deg8, dinv);
    k_coef <<<egrid, 256, 0, stream>>>(row, col, ea, dinv, coef8);
    k_csum <<<NB, 256, 0, stream>>>(coef8, dinv, c);
    k_conv6<<<NB * GRP, 256, 0, stream>>>(x, cw, cb, c, v16);
    k_out  <<<1, 128, 0, stream>>>(v16, gW, gb, out);
  }
}

// Round 6
// 266.791 us; speedup vs baseline: 1.6622x; 1.0378x over previous
//
#include <hip/hip_runtime.h>

#define NN 50000
#define NP 50176        // padded node stride (multiple of 256)
#define TT 518
#define KC 32
#define LL 163
#define HH 128
#define EE 1600000
#define NB 196          // node blocks: 196*256 = 50176 >= NN
#define NCOPY 8

// ---- chunked-LDS scatter (no global atomics) ----
#define CKN 4           // node chunks
#define CSZ 12544       // nodes/chunk (4*12544 = 50176), LDS acc = 50176 B
#define PSL 128         // edge slices (partials per chunk)
#define GSC (CKN*PSL)   // 512 blocks
#define ESL (EE/PSL)    // 12500 edges per slice (divisible by 4)
#define PQ 4            // p-quarters for the two-stage partial reduction

// ---- conv7: conv4 geometry, launch_bounds(256,1) ----
#define GRP 7           // l-groups, one block each: grid = NB*GRP = 1372
#define LPB 24          // l's per block (7*24 = 168 >= 163)
#define WIN 101         // window: 3*23 + 32 = 101 floats
#define VS 16           // v accumulator stripes
#define VSTR 192        // stripe stride (>= LL, 16B-aligned)

// deg partials: block (chunk=b&3, p=b>>2) scans slice p, bins col hits into
// LDS, flushes private partial with plain stores.  Software-pipelined: next
// iteration's edge loads issue BEFORE current atomics (halves exposed latency
// at the 8-waves/CU occupancy this kernel runs at).
__global__ __launch_bounds__(256) void k_deg_part(const int* __restrict__ col,
                                                  const float* __restrict__ ea,
                                                  float* __restrict__ part) {
  __shared__ float acc[CSZ];
  int tid = threadIdx.x;
  for (int j = tid; j < CSZ; j += 256) acc[j] = 0.f;
  __syncthreads();
  int chunk = blockIdx.x & (CKN - 1);
  int base = chunk * CSZ;
  const int4*   c4p = (const int4*)col + (blockIdx.x >> 2) * (ESL / 4);
  const float4* a4p = (const float4*)ea + (blockIdx.x >> 2) * (ESL / 4);
  int i = tid;
  bool valid = i < ESL / 4;
  int4 c4; float4 a4;
  if (valid) { c4 = c4p[i]; a4 = a4p[i]; }
  while (valid) {
    int inext = i + 256;
    bool vnext = inext < ESL / 4;
    int4 c4n; float4 a4n;
    if (vnext) { c4n = c4p[inext]; a4n = a4p[inext]; }
    unsigned jx = (unsigned)(c4.x - base);
    unsigned jy = (unsigned)(c4.y - base);
    unsigned jz = (unsigned)(c4.z - base);
    unsigned jw = (unsigned)(c4.w - base);
    if (jx < CSZ) atomicAdd(&acc[jx], a4.x);
    if (jy < CSZ) atomicAdd(&acc[jy], a4.y);
    if (jz < CSZ) atomicAdd(&acc[jz], a4.z);
    if (jw < CSZ) atomicAdd(&acc[jw], a4.w);
    i = inext; valid = vnext; c4 = c4n; a4 = a4n;
  }
  __syncthreads();
  float* out = part + (size_t)blockIdx.x * CSZ;
  for (int j = tid; j < CSZ; j += 256) out[j] = acc[j];
}

// stage-A partial reduction: block (nb, q) sums 32 slices for 256 nodes.
// Replaces the 128-deep strided sum in k_dinv2/k_csum2 (0.77 blocks/CU,
// ~13us of exposed latency) with 784 blocks = 3/CU, ILP-4, 8 rounds.
__global__ __launch_bounds__(256) void k_psum(const float* __restrict__ part,
                                              float* __restrict__ part2) {
  int b = blockIdx.x;
  int nb = b % NB, q = b / NB;     // q in 0..3
  int i = nb * 256 + threadIdx.x;
  if (i >= NN) return;
  int chunk = i / CSZ, j = i - chunk * CSZ;
  const float* base = part + (size_t)chunk * CSZ + j;
  int p0 = q * (PSL / PQ);
  float s0 = 0.f, s1 = 0.f, s2 = 0.f, s3 = 0.f;
#pragma unroll
  for (int p = 0; p < PSL / PQ; p += 4) {
    s0 += base[(size_t)(p0 + p + 0) * (CKN * CSZ)];
    s1 += base[(size_t)(p0 + p + 1) * (CKN * CSZ)];
    s2 += base[(size_t)(p0 + p + 2) * (CKN * CSZ)];
    s3 += base[(size_t)(p0 + p + 3) * (CKN * CSZ)];
  }
  part2[(size_t)q * NP + i] = (s0 + s1) + (s2 + s3);
}

// dinv[i] = rsqrt(1 + sum_q part2[q][i]); also zeroes v16 (saves a dispatch)
__global__ __launch_bounds__(256) void k_dinv3(const float* __restrict__ part2,
                                               float* __restrict__ dinv,
                                               float* __restrict__ v16) {
  int tid = threadIdx.x;
  if (blockIdx.x < (VS * VSTR) / 256) v16[blockIdx.x * 256 + tid] = 0.f;
  int i = blockIdx.x * 256 + tid;
  if (i >= NN) return;
  float s = part2[i] + part2[NP + i] + part2[2 * NP + i] + part2[3 * NP + i];
  dinv[i] = rsqrtf(1.0f + s);
}

// coef partials: acc[row] += ea * dinv[col]; dinv[row] folded into k_csum3.
// Software-pipelined like k_deg_part; the dinv gathers for iteration i issue
// right after the next-iteration streaming loads.
__global__ __launch_bounds__(256) void k_coef_part(const int* __restrict__ row,
                                                   const int* __restrict__ col,
                                                   const float* __restrict__ ea,
                                                   const float* __restrict__ dinv,
                                                   float* __restrict__ part) {
  __shared__ float acc[CSZ];
  int tid = threadIdx.x;
  for (int j = tid; j < CSZ; j += 256) acc[j] = 0.f;
  __syncthreads();
  int chunk = blockIdx.x & (CKN - 1);
  int base = chunk * CSZ;
  const int4*   r4p = (const int4*)row + (blockIdx.x >> 2) * (ESL / 4);
  const int4*   c4p = (const int4*)col + (blockIdx.x >> 2) * (ESL / 4);
  const float4* a4p = (const float4*)ea + (blockIdx.x >> 2) * (ESL / 4);
  int i = tid;
  bool valid = i < ESL / 4;
  int4 r4, c4; float4 a4;
  if (valid) { r4 = r4p[i]; c4 = c4p[i]; a4 = a4p[i]; }
  while (valid) {
    int inext = i + 256;
    bool vnext = inext < ESL / 4;
    int4 r4n, c4n; float4 a4n;
    if (vnext) { r4n = r4p[inext]; c4n = c4p[inext]; a4n = a4p[inext]; }
    float dx = dinv[c4.x], dy = dinv[c4.y], dz = dinv[c4.z], dw = dinv[c4.w];
    unsigned jx = (unsigned)(r4.x - base);
    unsigned jy = (unsigned)(r4.y - base);
    unsigned jz = (unsigned)(r4.z - base);
    unsigned jw = (unsigned)(r4.w - base);
    if (jx < CSZ) atomicAdd(&acc[jx], a4.x * dx);
    if (jy < CSZ) atomicAdd(&acc[jy], a4.y * dy);
    if (jz < CSZ) atomicAdd(&acc[jz], a4.z * dz);
    if (jw < CSZ) atomicAdd(&acc[jw], a4.w * dw);
    i = inext; valid = vnext; r4 = r4n; c4 = c4n; a4 = a4n;
  }
  __syncthreads();
  float* out = part + (size_t)blockIdx.x * CSZ;
  for (int j = tid; j < CSZ; j += 256) out[j] = acc[j];
}

// c[i] = dinv[i]^2 + dinv[i] * sum_q part2[q][i]
__global__ __launch_bounds__(256) void k_csum3(const float* __restrict__ part2,
                                               const float* __restrict__ dinv,
                                               float* __restrict__ c) {
  int i = blockIdx.x * 256 + threadIdx.x;
  if (i >= NN) return;
  float s = part2[i] + part2[NP + i] + part2[2 * NP + i] + part2[3 * NP + i];
  float di = dinv[i];
  c[i] = di * di + di * s;
}

// ---- fallback path (global-atomic version) if ws is too small ----
__global__ __launch_bounds__(256) void k_deg(const int* __restrict__ col,
                                             const float* __restrict__ ea,
                                             float* __restrict__ deg8) {
  int i = blockIdx.x * 256 + threadIdx.x;
  float* d = deg8 + (blockIdx.x & 7) * NP;
  if (i < EE / 4) {
    int4   c4 = ((const int4*)col)[i];
    float4 a4 = ((const float4*)ea)[i];
    atomicAdd(&d[c4.x], a4.x);
    atomicAdd(&d[c4.y], a4.y);
    atomicAdd(&d[c4.z], a4.z);
    atomicAdd(&d[c4.w], a4.w);
  }
}
__global__ __launch_bounds__(256) void k_dinv(const float* __restrict__ deg8,
                                              float* __restrict__ dinv) {
  int i = blockIdx.x * 256 + threadIdx.x;
  if (i < NN) {
    float s = 1.0f;
#pragma unroll
    for (int j = 0; j < NCOPY; ++j) s += deg8[j * NP + i];
    dinv[i] = rsqrtf(s);
  }
}
__global__ __launch_bounds__(256) void k_coef(const int* __restrict__ row,
                                              const int* __restrict__ col,
                                              const float* __restrict__ ea,
                                              const float* __restrict__ dinv,
                                              float* __restrict__ coef8) {
  int i = blockIdx.x * 256 + threadIdx.x;
  float* cf = coef8 + (blockIdx.x & 7) * NP;
  if (i < EE / 4) {
    int4   r4 = ((const int4*)row)[i];
    int4   c4 = ((const int4*)col)[i];
    float4 a4 = ((const float4*)ea)[i];
    atomicAdd(&cf[r4.x], a4.x * dinv[c4.x] * dinv[r4.x]);
    atomicAdd(&cf[r4.y], a4.y * dinv[c4.y] * dinv[r4.y]);
    atomicAdd(&cf[r4.z], a4.z * dinv[c4.z] * dinv[r4.z]);
    atomicAdd(&cf[r4.w], a4.w * dinv[c4.w] * dinv[r4.w]);
  }
}
__global__ __launch_bounds__(256) void k_csum(const float* __restrict__ coef8,
                                              const float* __restrict__ dinv,
                                              float* __restrict__ c) {
  int i = blockIdx.x * 256 + threadIdx.x;
  if (i < NN) {
    float di = dinv[i];
    float s = di * di;
#pragma unroll
    for (int j = 0; j < NCOPY; ++j) s += coef8[j * NP + i];
    c[i] = s;
  }
}

// v[l] += sum_n c[n]*relu(conv(x,w)+b)[l].
// conv7 = conv4 (verified 60.3us) with ONE change: __launch_bounds__(256,1).
// R3 evidence: under (256,2) the allocator capped VGPR at 128 < the ~145
// live floats (101 window + 32 w + acc), so it CHAINED loads (~420B in
// flight/wave -> 1.57 TB/s, latency-bound).  Under (256,1) the allocator
// demonstrably reaches VGPR~168 (R2/conv3), which fits this window ->
// all 101 x-loads batch above sched_barrier like the proven 53-load
// ancestor (~5.2 TB/s).  2-3 waves/SIMD with 26KB/wave in flight is
// far past the BW-latency product -> BW-bound, not latency-bound.
// R5 lesson: NO LDS w-staging (conv6 regression); R4: NO register shifting.
__global__ __launch_bounds__(256, 1) void k_conv7(const float* __restrict__ x,
                                                  const float* __restrict__ cw,
                                                  const float* __restrict__ cb,
                                                  const float* __restrict__ c,
                                                  float* __restrict__ v16) {
  __shared__ float vloc[LPB];
  int tid = threadIdx.x;
  if (tid < LPB) vloc[tid] = 0.f;
  __syncthreads();

  int nb = blockIdx.x % NB;
  int g  = blockIdx.x / NB;        // 0..6
  int n = nb * 256 + tid;
  int nc = n < NN ? n : NN - 1;    // clamp for safe loads; cn=0 kills contrib
  float cn = n < NN ? c[n] : 0.f;
  float bn = cb[nc];

  float w[KC];
  const float4* w4 = (const float4*)(cw + (size_t)nc * KC);
#pragma unroll
  for (int k = 0; k < KC / 4; ++k) {
    float4 t = w4[k];
    w[4 * k] = t.x; w[4 * k + 1] = t.y; w[4 * k + 2] = t.z; w[4 * k + 3] = t.w;
  }

  // register window: t in [72g, 72g+101); clamp pollutes only l >= 163
  const float* xp = x + nc;
  float xs[WIN];
#pragma unroll
  for (int j = 0; j < WIN; ++j) {
    int t = 72 * g + j;
    t = t < TT ? t : TT - 1;
    xs[j] = xp[(size_t)t * NN];
  }
  __builtin_amdgcn_sched_barrier(0);   // loads stay ABOVE, compute BELOW

  int lane = tid & 63;
#pragma unroll
  for (int cc = 0; cc < 3; ++cc) {
    float accv[8];
#pragma unroll
    for (int u = 0; u < 8; ++u) {
      float h = 0.f;
#pragma unroll
      for (int k = 0; k < KC; ++k) h += xs[24 * cc + 3 * u + k] * w[k];
      h += bn;
      h = h > 0.f ? h : 0.f;
      accv[u] = cn * h;
    }
#pragma unroll
    for (int u = 0; u < 8; ++u) {
      float val = accv[u];
      val += __shfl_xor(val, 1, 64);
      val += __shfl_xor(val, 2, 64);
      val += __shfl_xor(val, 4, 64);
      val += __shfl_xor(val, 8, 64);
      val += __shfl_xor(val, 16, 64);
      val += __shfl_xor(val, 32, 64);
      if (lane == 0) atomicAdd(&vloc[8 * cc + u], val);
    }
  }
  __syncthreads();
  float* vdst = v16 + (blockIdx.x & (VS - 1)) * VSTR;
  if (tid < LPB) {
    int l = LPB * g + tid;
    if (l < LL) atomicAdd(&vdst[l], vloc[tid]);
  }
}

// out[h] = (sum_l (sum_j v16[j][l]) * W[l][h]) / N + gcn_b[h]
__global__ __launch_bounds__(128) void k_out(const float* __restrict__ v16,
                                             const float* __restrict__ W,
                                             const float* __restrict__ b,
                                             float* __restrict__ out) {
  __shared__ float vs[LL];
  int h = threadIdx.x;
  for (int l = h; l < LL; l += 128) {
    float s = 0.f;
#pragma unroll
    for (int j = 0; j < VS; ++j) s += v16[j * VSTR + l];
    vs[l] = s;
  }
  __syncthreads();
  float s = 0.f;
  for (int l = 0; l < LL; ++l) s += vs[l] * W[l * HH + h];
  out[h] = s * (1.0f / NN) + b[h];
}

extern "C" void kernel_launch(void* const* d_in, const int* in_sizes, int n_in,
                              void* d_out, int out_size, void* d_ws, size_t ws_size,
                              hipStream_t stream) {
  const float* x  = (const float*)d_in[0];
  const int*   ei = (const int*)d_in[1];
  const float* ea = (const float*)d_in[2];
  const float* cw = (const float*)d_in[3];
  const float* cb = (const float*)d_in[4];
  const float* gW = (const float*)d_in[5];
  const float* gb = (const float*)d_in[6];
  float* out = (float*)d_out;

  const int* row = ei;
  const int* col = ei + EE;
  float* ws = (float*)d_ws;

  size_t need_new = ((size_t)GSC * CSZ + VS * VSTR + (2 + PQ) * NP) * sizeof(float);
  if (ws_size >= need_new) {
    float* part  = ws;                          // GSC*CSZ floats (reused deg->coef)
    float* v16   = ws + (size_t)GSC * CSZ;      // VS*VSTR floats
    float* dinv  = v16 + VS * VSTR;             // NP floats
    float* c     = dinv + NP;                   // NP floats
    float* part2 = c + NP;                      // PQ*NP floats
    k_deg_part <<<GSC, 256, 0, stream>>>(col, ea, part);
    k_psum     <<<NB * PQ, 256, 0, stream>>>(part, part2);
    k_dinv3    <<<NB, 256, 0, stream>>>(part2, dinv, v16);
    k_coef_part<<<GSC, 256, 0, stream>>>(row, col, ea, dinv, part);
    k_psum     <<<NB * PQ, 256, 0, stream>>>(part, part2);
    k_csum3    <<<NB, 256, 0, stream>>>(part2, dinv, c);
    k_conv7    <<<NB * GRP, 256, 0, stream>>>(x, cw, cb, c, v16);
    k_out      <<<1, 128, 0, stream>>>(v16, gW, gb, out);
  } else {
    float* deg8  = ws;
    float* coef8 = ws + NCOPY * NP;
    float* v16   = ws + 2 * NCOPY * NP;
    float* dinv  = v16 + VS * VSTR;
    float* c     = dinv + NP;
    hipMemsetAsync(deg8, 0, (2 * NCOPY * NP + VS * VSTR) * sizeof(float), stream);
    int egrid = (EE / 4 + 255) / 256;
    k_deg  <<<egrid, 256, 0, stream>>>(col, ea, deg8);
    k_dinv <<<NB, 256, 0, stream>>>(deg8, dinv);
    k_coef <<<egrid, 256, 0, stream>>>(row, col, ea, dinv, coef8);
    k_csum <<<NB, 256, 0, stream>>>(coef8, dinv, c);
    k_conv7<<<NB * GRP, 256, 0, stream>>>(x, cw, cb, c, v16);
    k_out  <<<1, 128, 0, stream>>>(v16, gW, gb, out);
  }
}